// Round 1
// baseline (4759.990 us; speedup 1.0000x reference)
//
#include <hip/hip_runtime.h>
#include <hip/hip_bf16.h>

// Problem constants
#define T_TOK 8192
#define E_EXP 8
#define D_HID 1024
#define F_FFN 4096
#define C_CAP 2048   // T * 2.0 / E

// ---------------------------------------------------------------------------
// Kernel 1: router gating. One wave (64 lanes) per token.
// Computes logits = x[t] . Wg (fp32), softmax over 8 experts,
// writes gatesT[e*T + t].
// ---------------------------------------------------------------------------
__global__ __launch_bounds__(256) void gating_kernel(
    const float* __restrict__ x, const float* __restrict__ Wg,
    float* __restrict__ gatesT)
{
    const int token = blockIdx.x * 4 + (threadIdx.x >> 6);
    const int lane  = threadIdx.x & 63;
    const float* xr = x + (size_t)token * D_HID;

    float acc[E_EXP];
#pragma unroll
    for (int e = 0; e < E_EXP; ++e) acc[e] = 0.0f;

    for (int c = 0; c < D_HID; c += 64) {
        float xv = xr[c + lane];
        const float* wr = Wg + (size_t)(c + lane) * E_EXP;
#pragma unroll
        for (int e = 0; e < E_EXP; ++e) acc[e] += xv * wr[e];
    }
#pragma unroll
    for (int e = 0; e < E_EXP; ++e) {
        for (int off = 32; off; off >>= 1) acc[e] += __shfl_down(acc[e], off);
    }
    if (lane == 0) {
        float m = acc[0];
#pragma unroll
        for (int e = 1; e < E_EXP; ++e) m = fmaxf(m, acc[e]);
        float ex[E_EXP];
        float s = 0.0f;
#pragma unroll
        for (int e = 0; e < E_EXP; ++e) { ex[e] = expf(acc[e] - m); s += ex[e]; }
        float inv = 1.0f / s;
#pragma unroll
        for (int e = 0; e < E_EXP; ++e) gatesT[(size_t)e * T_TOK + token] = ex[e] * inv;
    }
}

// ---------------------------------------------------------------------------
// Kernel 2: aux loss. frac_routed[e] == C/T exactly (top_k indices distinct),
// so aux = E * (C/T) * (sum of all gates) / T  = 2 * s / T here.
// Single block reduction.
// ---------------------------------------------------------------------------
__global__ __launch_bounds__(256) void aux_kernel(
    const float* __restrict__ gatesT, float* __restrict__ aux_out)
{
    float s = 0.0f;
    for (int i = threadIdx.x; i < T_TOK * E_EXP; i += 256) s += gatesT[i];
    for (int off = 32; off; off >>= 1) s += __shfl_down(s, off);
    __shared__ float red[4];
    if ((threadIdx.x & 63) == 0) red[threadIdx.x >> 6] = s;
    __syncthreads();
    if (threadIdx.x == 0) {
        float tot = red[0] + red[1] + red[2] + red[3];
        float frac = (float)C_CAP / (float)T_TOK;
        aux_out[0] = (float)E_EXP * frac * (tot / (float)T_TOK);
    }
}

// ---------------------------------------------------------------------------
// Kernel 3: exact per-expert top-C via bitonic sort of packed 64-bit keys.
// key = (monotone_float_bits << 32) | (T-1-idx)  -> descending sort gives
// values desc, ties broken by smaller idx first (matches jax.lax.top_k).
// One block per expert; 8192 keys in 64 KB LDS.
// ---------------------------------------------------------------------------
__global__ __launch_bounds__(1024) void topk_kernel(
    const float* __restrict__ gatesT, int* __restrict__ topidx,
    float* __restrict__ topval)
{
    __shared__ unsigned long long keys[T_TOK];
    const int e = blockIdx.x;
    const float* row = gatesT + (size_t)e * T_TOK;

    for (int i = threadIdx.x; i < T_TOK; i += blockDim.x) {
        unsigned int b = __float_as_uint(row[i]);
        b = (b & 0x80000000u) ? ~b : (b | 0x80000000u);  // monotone map
        keys[i] = ((unsigned long long)b << 32) | (unsigned int)(T_TOK - 1 - i);
    }
    __syncthreads();

    for (int k = 2; k <= T_TOK; k <<= 1) {
        for (int j = k >> 1; j > 0; j >>= 1) {
            for (int i = threadIdx.x; i < T_TOK; i += blockDim.x) {
                int p = i ^ j;
                if (p > i) {
                    bool desc = ((i & k) == 0);
                    unsigned long long a = keys[i];
                    unsigned long long b = keys[p];
                    bool sw = desc ? (a < b) : (a > b);
                    if (sw) { keys[i] = b; keys[p] = a; }
                }
            }
            __syncthreads();
        }
    }

    for (int c = threadIdx.x; c < C_CAP; c += blockDim.x) {
        unsigned long long kk = keys[c];
        int idx = T_TOK - 1 - (int)(kk & 0xFFFFFFFFu);
        unsigned int b = (unsigned int)(kk >> 32);
        b = (b & 0x80000000u) ? (b & 0x7FFFFFFFu) : ~b;  // inverse monotone
        topidx[e * C_CAP + c] = idx;
        topval[e * C_CAP + c] = __uint_as_float(b);
    }
}

// ---------------------------------------------------------------------------
// Kernel 4: GEMM1 per expert: h = gelu_tanh(xg @ W1[e] + b1[e])
// A = gathered x rows [C, D], B = W1[e] [D, F] row-major. 64x64 tile, BK=16,
// 256 threads, 4x4 micro-tile, fp32.
// ---------------------------------------------------------------------------
__device__ __forceinline__ float gelu_tanh(float v) {
    // jax.nn.gelu default (approximate=True)
    float t = tanhf(0.7978845608028654f * (v + 0.044715f * v * v * v));
    return 0.5f * v * (1.0f + t);
}

__global__ __launch_bounds__(256) void ffn1_kernel(
    const float* __restrict__ x, const float* __restrict__ W1,
    const float* __restrict__ b1, const int* __restrict__ topidx,
    float* __restrict__ h, int e)
{
    __shared__ float As[16][68];
    __shared__ float Bs[16][68];
    const int tid = threadIdx.x;
    const int n0 = blockIdx.x * 64;
    const int m0 = blockIdx.y * 64;
    const float* W = W1 + (size_t)e * D_HID * F_FFN;

    const int lm = tid >> 2;          // A row within tile (0..63)
    const int lk = (tid & 3) * 4;     // A k-quad
    const int token = topidx[e * C_CAP + m0 + lm];
    const float* xrow = x + (size_t)token * D_HID;

    const int bk = tid >> 4;          // B k row (0..15)
    const int bn = (tid & 15) * 4;    // B n-quad

    const int ty = tid >> 4, tx = tid & 15;
    float acc[4][4] = {};

    for (int k0 = 0; k0 < D_HID; k0 += 16) {
        float4 av = *(const float4*)(xrow + k0 + lk);
        As[lk + 0][lm] = av.x; As[lk + 1][lm] = av.y;
        As[lk + 2][lm] = av.z; As[lk + 3][lm] = av.w;
        *(float4*)&Bs[bk][bn] = *(const float4*)(W + (size_t)(k0 + bk) * F_FFN + n0 + bn);
        __syncthreads();
#pragma unroll
        for (int k = 0; k < 16; ++k) {
            float a[4], b[4];
            *(float4*)a = *(const float4*)&As[k][ty * 4];
            *(float4*)b = *(const float4*)&Bs[k][tx * 4];
#pragma unroll
            for (int i = 0; i < 4; ++i)
#pragma unroll
                for (int j = 0; j < 4; ++j) acc[i][j] += a[i] * b[j];
        }
        __syncthreads();
    }

#pragma unroll
    for (int i = 0; i < 4; ++i) {
        int c = m0 + ty * 4 + i;
#pragma unroll
        for (int j = 0; j < 4; ++j) {
            int n = n0 + tx * 4 + j;
            float v = acc[i][j] + b1[e * F_FFN + n];
            h[(size_t)c * F_FFN + n] = gelu_tanh(v);
        }
    }
}

// ---------------------------------------------------------------------------
// Kernel 5: GEMM2 per expert: yo = h @ W2[e] + b2[e]; out[token] += yo * gate
// A = h [C, F], B = W2[e] [F, D]. Plain RMW (per-expert indices distinct;
// experts serialize on the stream).
// ---------------------------------------------------------------------------
__global__ __launch_bounds__(256) void ffn2_kernel(
    const float* __restrict__ h, const float* __restrict__ W2,
    const float* __restrict__ b2, const int* __restrict__ topidx,
    const float* __restrict__ topval, float* __restrict__ out, int e)
{
    __shared__ float As[16][68];
    __shared__ float Bs[16][68];
    const int tid = threadIdx.x;
    const int n0 = blockIdx.x * 64;
    const int m0 = blockIdx.y * 64;
    const float* W = W2 + (size_t)e * F_FFN * D_HID;

    const int lm = tid >> 2;
    const int lk = (tid & 3) * 4;
    const float* arow = h + (size_t)(m0 + lm) * F_FFN;

    const int bk = tid >> 4;
    const int bn = (tid & 15) * 4;

    const int ty = tid >> 4, tx = tid & 15;
    float acc[4][4] = {};

    for (int k0 = 0; k0 < F_FFN; k0 += 16) {
        float4 av = *(const float4*)(arow + k0 + lk);
        As[lk + 0][lm] = av.x; As[lk + 1][lm] = av.y;
        As[lk + 2][lm] = av.z; As[lk + 3][lm] = av.w;
        *(float4*)&Bs[bk][bn] = *(const float4*)(W + (size_t)(k0 + bk) * D_HID + n0 + bn);
        __syncthreads();
#pragma unroll
        for (int k = 0; k < 16; ++k) {
            float a[4], b[4];
            *(float4*)a = *(const float4*)&As[k][ty * 4];
            *(float4*)b = *(const float4*)&Bs[k][tx * 4];
#pragma unroll
            for (int i = 0; i < 4; ++i)
#pragma unroll
                for (int j = 0; j < 4; ++j) acc[i][j] += a[i] * b[j];
        }
        __syncthreads();
    }

#pragma unroll
    for (int i = 0; i < 4; ++i) {
        int c = m0 + ty * 4 + i;
        int token = topidx[e * C_CAP + c];
        float w = topval[e * C_CAP + c];
        float* orow = out + (size_t)token * D_HID;
#pragma unroll
        for (int j = 0; j < 4; ++j) {
            int n = n0 + tx * 4 + j;
            float v = (acc[i][j] + b2[e * D_HID + n]) * w;
            orow[n] += v;   // safe: tokens distinct within expert; experts serialize
        }
    }
}

// ---------------------------------------------------------------------------
extern "C" void kernel_launch(void* const* d_in, const int* in_sizes, int n_in,
                              void* d_out, int out_size, void* d_ws, size_t ws_size,
                              hipStream_t stream) {
    const float* x  = (const float*)d_in[0];   // [8,1024,1024] -> [T, D]
    const float* Wg = (const float*)d_in[1];   // [D, E]
    const float* W1 = (const float*)d_in[2];   // [E, D, F]
    const float* b1 = (const float*)d_in[3];   // [E, F]
    const float* W2 = (const float*)d_in[4];   // [E, F, D]
    const float* b2 = (const float*)d_in[5];   // [E, D]
    float* out = (float*)d_out;                // [T*D] out ++ [1] aux

    // Workspace layout (fp32 words)
    float* gatesT = (float*)d_ws;                        // E*T
    int*   topidx = (int*)(gatesT + E_EXP * T_TOK);      // E*C
    float* topval = (float*)(topidx + E_EXP * C_CAP);    // E*C
    float* h      = topval + E_EXP * C_CAP;              // C*F (per-expert, reused)

    // Zero the output (harness poisons it before every launch)
    hipMemsetAsync(d_out, 0, (size_t)out_size * sizeof(float), stream);

    gating_kernel<<<T_TOK / 4, 256, 0, stream>>>(x, Wg, gatesT);
    aux_kernel<<<1, 256, 0, stream>>>(gatesT, out + (size_t)T_TOK * D_HID);
    topk_kernel<<<E_EXP, 1024, 0, stream>>>(gatesT, topidx, topval);

    dim3 g1(F_FFN / 64, C_CAP / 64);   // (64, 32)
    dim3 g2(D_HID / 64, C_CAP / 64);   // (16, 32)
    for (int e = 0; e < E_EXP; ++e) {
        ffn1_kernel<<<g1, 256, 0, stream>>>(x, W1, b1, topidx, h, e);
        ffn2_kernel<<<g2, 256, 0, stream>>>(h, W2, b2, topidx, topval, out, e);
    }
}

// Round 2
// 1067.799 us; speedup vs baseline: 4.4578x; 4.4578x over previous
//
#include <hip/hip_runtime.h>
#include <hip/hip_bf16.h>

// Problem constants
#define T_TOK 8192
#define E_EXP 8
#define D_HID 1024
#define F_FFN 4096
#define C_CAP 2048   // T * 2.0 / E

// MFMA GEMM tiling
#define TM 128
#define TN 128
#define BK 32

typedef __attribute__((ext_vector_type(8))) short bf16x8;  // 8 bf16 (4 VGPRs)
typedef __attribute__((ext_vector_type(4))) float f32x4;   // 4 fp32 acc

// Async global->LDS, 16 B per lane. LDS dest must be wave-uniform base;
// HW deposits at base + lane*16. Source address may be per-lane (gather OK).
__device__ __forceinline__ void load_lds16(const void* g, void* l) {
    __builtin_amdgcn_global_load_lds(
        (const __attribute__((address_space(1))) unsigned int*)g,
        (__attribute__((address_space(3))) unsigned int*)l, 16, 0, 0);
}

__device__ __forceinline__ float gelu_tanh(float v) {
    float t = tanhf(0.7978845608028654f * (v + 0.044715f * v * v * v));
    return 0.5f * v * (1.0f + t);
}

// ---------------------------------------------------------------------------
// Kernel 1: router gating (fp32 exact). One wave per token.
// ---------------------------------------------------------------------------
__global__ __launch_bounds__(256) void gating_kernel(
    const float* __restrict__ x, const float* __restrict__ Wg,
    float* __restrict__ gatesT)
{
    const int token = blockIdx.x * 4 + (threadIdx.x >> 6);
    const int lane  = threadIdx.x & 63;
    const float* xr = x + (size_t)token * D_HID;

    float acc[E_EXP];
#pragma unroll
    for (int e = 0; e < E_EXP; ++e) acc[e] = 0.0f;

    for (int c = 0; c < D_HID; c += 64) {
        float xv = xr[c + lane];
        const float* wr = Wg + (size_t)(c + lane) * E_EXP;
#pragma unroll
        for (int e = 0; e < E_EXP; ++e) acc[e] += xv * wr[e];
    }
#pragma unroll
    for (int e = 0; e < E_EXP; ++e) {
        for (int off = 32; off; off >>= 1) acc[e] += __shfl_down(acc[e], off);
    }
    if (lane == 0) {
        float m = acc[0];
#pragma unroll
        for (int e = 1; e < E_EXP; ++e) m = fmaxf(m, acc[e]);
        float ex[E_EXP];
        float s = 0.0f;
#pragma unroll
        for (int e = 0; e < E_EXP; ++e) { ex[e] = expf(acc[e] - m); s += ex[e]; }
        float inv = 1.0f / s;
#pragma unroll
        for (int e = 0; e < E_EXP; ++e) gatesT[(size_t)e * T_TOK + token] = ex[e] * inv;
    }
}

// ---------------------------------------------------------------------------
// Kernel 2: aux loss = E * (C/T) * mean(gates)  (frac_routed == C/T exactly)
// ---------------------------------------------------------------------------
__global__ __launch_bounds__(256) void aux_kernel(
    const float* __restrict__ gatesT, float* __restrict__ aux_out)
{
    float s = 0.0f;
    for (int i = threadIdx.x; i < T_TOK * E_EXP; i += 256) s += gatesT[i];
    for (int off = 32; off; off >>= 1) s += __shfl_down(s, off);
    __shared__ float red[4];
    if ((threadIdx.x & 63) == 0) red[threadIdx.x >> 6] = s;
    __syncthreads();
    if (threadIdx.x == 0) {
        float tot = red[0] + red[1] + red[2] + red[3];
        float frac = (float)C_CAP / (float)T_TOK;
        aux_out[0] = (float)E_EXP * frac * (tot / (float)T_TOK);
    }
}

// ---------------------------------------------------------------------------
// Kernel 3: exact per-expert top-C bitonic sort (64-bit keys, jax tie-break)
// ---------------------------------------------------------------------------
__global__ __launch_bounds__(1024) void topk_kernel(
    const float* __restrict__ gatesT, int* __restrict__ topidx,
    float* __restrict__ topval)
{
    __shared__ unsigned long long keys[T_TOK];
    const int e = blockIdx.x;
    const float* row = gatesT + (size_t)e * T_TOK;

    for (int i = threadIdx.x; i < T_TOK; i += blockDim.x) {
        unsigned int b = __float_as_uint(row[i]);
        b = (b & 0x80000000u) ? ~b : (b | 0x80000000u);
        keys[i] = ((unsigned long long)b << 32) | (unsigned int)(T_TOK - 1 - i);
    }
    __syncthreads();

    for (int k = 2; k <= T_TOK; k <<= 1) {
        for (int j = k >> 1; j > 0; j >>= 1) {
            for (int i = threadIdx.x; i < T_TOK; i += blockDim.x) {
                int p = i ^ j;
                if (p > i) {
                    bool desc = ((i & k) == 0);
                    unsigned long long a = keys[i];
                    unsigned long long b = keys[p];
                    bool sw = desc ? (a < b) : (a > b);
                    if (sw) { keys[i] = b; keys[p] = a; }
                }
            }
            __syncthreads();
        }
    }

    for (int c = threadIdx.x; c < C_CAP; c += blockDim.x) {
        unsigned long long kk = keys[c];
        int idx = T_TOK - 1 - (int)(kk & 0xFFFFFFFFu);
        unsigned int b = (unsigned int)(kk >> 32);
        b = (b & 0x80000000u) ? (b & 0x7FFFFFFFu) : ~b;
        topidx[e * C_CAP + c] = idx;
        topval[e * C_CAP + c] = __uint_as_float(b);
    }
}

// ---------------------------------------------------------------------------
// Kernel 4: fp32 -> bf16 elementwise (x), vectorized.
// ---------------------------------------------------------------------------
__global__ __launch_bounds__(256) void cvt_bf16_kernel(
    const float* __restrict__ in, __hip_bfloat16* __restrict__ out, int n4)
{
    int i = blockIdx.x * 256 + threadIdx.x;
    if (i >= n4) return;
    float4 v = ((const float4*)in)[i];
    union { __hip_bfloat16 h[4]; short4 s; } u;
    u.h[0] = __float2bfloat16(v.x); u.h[1] = __float2bfloat16(v.y);
    u.h[2] = __float2bfloat16(v.z); u.h[3] = __float2bfloat16(v.w);
    ((short4*)out)[i] = u.s;
}

// ---------------------------------------------------------------------------
// Kernel 5: per-expert transpose + convert: in [E][R][Cn] fp32 ->
// out [E][Cn][R] bf16 (weights to [N][K] so MFMA B-fragments are k-contiguous)
// ---------------------------------------------------------------------------
__global__ __launch_bounds__(256) void transpose_bf16_kernel(
    const float* __restrict__ in, __hip_bfloat16* __restrict__ out,
    int R, int Cn)
{
    __shared__ float tile[32][33];
    const int e = blockIdx.z;
    in  += (size_t)e * R * Cn;
    out += (size_t)e * R * Cn;
    const int c0 = blockIdx.x * 32, r0 = blockIdx.y * 32;
    const int tx = threadIdx.x & 31, ty = threadIdx.x >> 5;  // 32 x 8
#pragma unroll
    for (int j = ty; j < 32; j += 8)
        tile[j][tx] = in[(size_t)(r0 + j) * Cn + c0 + tx];
    __syncthreads();
#pragma unroll
    for (int j = ty; j < 32; j += 8)
        out[(size_t)(c0 + j) * R + r0 + tx] = __float2bfloat16(tile[tx][j]);
}

// ---------------------------------------------------------------------------
// Kernel 6: GEMM1 (all experts): h[e] = gelu(gather(x)[C,D] @ W1t[e]^T + b1[e])
// A gathered from x_bf via topidx; W1t is [E][F][D] bf16 (n-major, k-contig).
// m97-style: 128x128 tile, BK=32, 4 waves, 4x4 of 16x16x32 MFMA per wave,
// global_load_lds width-16 staging.
// ---------------------------------------------------------------------------
__global__ __launch_bounds__(256) void gemm1_kernel(
    const __hip_bfloat16* __restrict__ xb,   // [T][D]
    const __hip_bfloat16* __restrict__ W1t,  // [E][F][D]
    const float* __restrict__ b1,            // [E][F]
    const int* __restrict__ topidx,          // [E][C]
    __hip_bfloat16* __restrict__ h)          // [E][C][F]
{
    __shared__ __hip_bfloat16 As[TM * BK];   // [128][32] row-major (m,k)
    __shared__ __hip_bfloat16 Bs[TN * BK];   // [128][32] row-major (n,k)

    const int e   = blockIdx.z;
    const int n0  = blockIdx.x * TN;
    const int m0  = blockIdx.y * TM;
    const int tid = threadIdx.x;
    const int w = tid >> 6, lane = tid & 63;

    // staging geometry: inst j covers 16 rows; lane -> (row, kspan)
    const int sr0 = (w * 2 + 0) * 16 + (lane >> 2);
    const int sr1 = (w * 2 + 1) * 16 + (lane >> 2);
    const int skp = (lane & 3) * 8;

    const __hip_bfloat16* W = W1t + (size_t)e * F_FFN * D_HID;

    const int tok0 = topidx[e * C_CAP + m0 + sr0];
    const int tok1 = topidx[e * C_CAP + m0 + sr1];
    const __hip_bfloat16* asrc0 = xb + (size_t)tok0 * D_HID + skp;
    const __hip_bfloat16* asrc1 = xb + (size_t)tok1 * D_HID + skp;
    const __hip_bfloat16* bsrc0 = W + (size_t)(n0 + sr0) * D_HID + skp;
    const __hip_bfloat16* bsrc1 = W + (size_t)(n0 + sr1) * D_HID + skp;

    __hip_bfloat16* adst0 = As + (w * 2 + 0) * 512;  // wave-uniform LDS bases
    __hip_bfloat16* adst1 = As + (w * 2 + 1) * 512;
    __hip_bfloat16* bdst0 = Bs + (w * 2 + 0) * 512;
    __hip_bfloat16* bdst1 = Bs + (w * 2 + 1) * 512;

    // compute geometry: wave (wr,wc) owns 64x64; frag row/col + k-quad
    const int wr = w >> 1, wc = w & 1;
    const int fr = lane & 15;
    const int fq = (lane >> 4) * 8;
    int aoff[4], boff[4];
#pragma unroll
    for (int i = 0; i < 4; ++i) {
        aoff[i] = (wr * 64 + i * 16 + fr) * BK + fq;
        boff[i] = (wc * 64 + i * 16 + fr) * BK + fq;
    }

    f32x4 acc[4][4];
#pragma unroll
    for (int mi = 0; mi < 4; ++mi)
#pragma unroll
        for (int ni = 0; ni < 4; ++ni) acc[mi][ni] = (f32x4){0.f, 0.f, 0.f, 0.f};

    for (int k0 = 0; k0 < D_HID; k0 += BK) {
        __syncthreads();
        load_lds16(asrc0 + k0, adst0);
        load_lds16(asrc1 + k0, adst1);
        load_lds16(bsrc0 + k0, bdst0);
        load_lds16(bsrc1 + k0, bdst1);
        __syncthreads();

        bf16x8 af[4], bfm[4];
#pragma unroll
        for (int i = 0; i < 4; ++i) af[i]  = *(const bf16x8*)(As + aoff[i]);
#pragma unroll
        for (int i = 0; i < 4; ++i) bfm[i] = *(const bf16x8*)(Bs + boff[i]);
#pragma unroll
        for (int mi = 0; mi < 4; ++mi)
#pragma unroll
            for (int ni = 0; ni < 4; ++ni)
                acc[mi][ni] = __builtin_amdgcn_mfma_f32_16x16x32_bf16(
                    af[mi], bfm[ni], acc[mi][ni], 0, 0, 0);
    }

    // epilogue: bias + gelu, bf16 store. C/D: col=lane&15, row=quad*4+reg
    const int q4 = (lane >> 4) * 4;
#pragma unroll
    for (int ni = 0; ni < 4; ++ni) {
        const int col = n0 + wc * 64 + ni * 16 + fr;
        const float bias = b1[e * F_FFN + col];
#pragma unroll
        for (int mi = 0; mi < 4; ++mi) {
#pragma unroll
            for (int r = 0; r < 4; ++r) {
                const int row = m0 + wr * 64 + mi * 16 + q4 + r;
                float v = acc[mi][ni][r] + bias;
                h[((size_t)e * C_CAP + row) * F_FFN + col] =
                    __float2bfloat16(gelu_tanh(v));
            }
        }
    }
}

// ---------------------------------------------------------------------------
// Kernel 7: GEMM2 (all experts): out[tok] += (h[e] @ W2t[e]^T + b2[e]) * gate
// A = h[e] [C][F] (k-contig), B = W2t [E][D][F] bf16 (n-major, k-contig).
// Scatter via fp32 atomicAdd (tokens can repeat across experts).
// ---------------------------------------------------------------------------
__global__ __launch_bounds__(256) void gemm2_kernel(
    const __hip_bfloat16* __restrict__ h,    // [E][C][F]
    const __hip_bfloat16* __restrict__ W2t,  // [E][D][F]
    const float* __restrict__ b2,            // [E][D]
    const int* __restrict__ topidx,          // [E][C]
    const float* __restrict__ topval,        // [E][C]
    float* __restrict__ out)                 // [T][D]
{
    __shared__ __hip_bfloat16 As[TM * BK];
    __shared__ __hip_bfloat16 Bs[TN * BK];

    const int e   = blockIdx.z;
    const int n0  = blockIdx.x * TN;
    const int m0  = blockIdx.y * TM;
    const int tid = threadIdx.x;
    const int w = tid >> 6, lane = tid & 63;

    const int sr0 = (w * 2 + 0) * 16 + (lane >> 2);
    const int sr1 = (w * 2 + 1) * 16 + (lane >> 2);
    const int skp = (lane & 3) * 8;

    const __hip_bfloat16* A = h + (size_t)e * C_CAP * F_FFN;
    const __hip_bfloat16* W = W2t + (size_t)e * D_HID * F_FFN;

    const __hip_bfloat16* asrc0 = A + (size_t)(m0 + sr0) * F_FFN + skp;
    const __hip_bfloat16* asrc1 = A + (size_t)(m0 + sr1) * F_FFN + skp;
    const __hip_bfloat16* bsrc0 = W + (size_t)(n0 + sr0) * F_FFN + skp;
    const __hip_bfloat16* bsrc1 = W + (size_t)(n0 + sr1) * F_FFN + skp;

    __hip_bfloat16* adst0 = As + (w * 2 + 0) * 512;
    __hip_bfloat16* adst1 = As + (w * 2 + 1) * 512;
    __hip_bfloat16* bdst0 = Bs + (w * 2 + 0) * 512;
    __hip_bfloat16* bdst1 = Bs + (w * 2 + 1) * 512;

    const int wr = w >> 1, wc = w & 1;
    const int fr = lane & 15;
    const int fq = (lane >> 4) * 8;
    int aoff[4], boff[4];
#pragma unroll
    for (int i = 0; i < 4; ++i) {
        aoff[i] = (wr * 64 + i * 16 + fr) * BK + fq;
        boff[i] = (wc * 64 + i * 16 + fr) * BK + fq;
    }

    f32x4 acc[4][4];
#pragma unroll
    for (int mi = 0; mi < 4; ++mi)
#pragma unroll
        for (int ni = 0; ni < 4; ++ni) acc[mi][ni] = (f32x4){0.f, 0.f, 0.f, 0.f};

    for (int k0 = 0; k0 < F_FFN; k0 += BK) {
        __syncthreads();
        load_lds16(asrc0 + k0, adst0);
        load_lds16(asrc1 + k0, adst1);
        load_lds16(bsrc0 + k0, bdst0);
        load_lds16(bsrc1 + k0, bdst1);
        __syncthreads();

        bf16x8 af[4], bfm[4];
#pragma unroll
        for (int i = 0; i < 4; ++i) af[i]  = *(const bf16x8*)(As + aoff[i]);
#pragma unroll
        for (int i = 0; i < 4; ++i) bfm[i] = *(const bf16x8*)(Bs + boff[i]);
#pragma unroll
        for (int mi = 0; mi < 4; ++mi)
#pragma unroll
            for (int ni = 0; ni < 4; ++ni)
                acc[mi][ni] = __builtin_amdgcn_mfma_f32_16x16x32_bf16(
                    af[mi], bfm[ni], acc[mi][ni], 0, 0, 0);
    }

    // epilogue: bias, gate-weight, atomic scatter-add
    const int q4 = (lane >> 4) * 4;
    float b2v[4];
#pragma unroll
    for (int ni = 0; ni < 4; ++ni)
        b2v[ni] = b2[e * D_HID + n0 + wc * 64 + ni * 16 + fr];

#pragma unroll
    for (int mi = 0; mi < 4; ++mi) {
#pragma unroll
        for (int r = 0; r < 4; ++r) {
            const int row = m0 + wr * 64 + mi * 16 + q4 + r;
            const int tok = topidx[e * C_CAP + row];
            const float g = topval[e * C_CAP + row];
            float* orow = out + (size_t)tok * D_HID;
#pragma unroll
            for (int ni = 0; ni < 4; ++ni) {
                const int col = n0 + wc * 64 + ni * 16 + fr;
                atomicAdd(orow + col, (acc[mi][ni][r] + b2v[ni]) * g);
            }
        }
    }
}

// ---------------------------------------------------------------------------
extern "C" void kernel_launch(void* const* d_in, const int* in_sizes, int n_in,
                              void* d_out, int out_size, void* d_ws, size_t ws_size,
                              hipStream_t stream) {
    const float* x  = (const float*)d_in[0];   // [T, D]
    const float* Wg = (const float*)d_in[1];   // [D, E]
    const float* W1 = (const float*)d_in[2];   // [E, D, F]
    const float* b1 = (const float*)d_in[3];   // [E, F]
    const float* W2 = (const float*)d_in[4];   // [E, F, D]
    const float* b2 = (const float*)d_in[5];   // [E, D]
    float* out = (float*)d_out;                // [T*D] out ++ [1] aux

    // Workspace layout
    char* p = (char*)d_ws;
    float* gatesT = (float*)p;            p += (size_t)E_EXP * T_TOK * 4;      // 256 KB
    int*   topidx = (int*)p;              p += (size_t)E_EXP * C_CAP * 4;      // 64 KB
    float* topval = (float*)p;            p += (size_t)E_EXP * C_CAP * 4;      // 64 KB
    __hip_bfloat16* x_bf = (__hip_bfloat16*)p;  p += (size_t)T_TOK * D_HID * 2;        // 16.8 MB
    __hip_bfloat16* W1t  = (__hip_bfloat16*)p;  p += (size_t)E_EXP * D_HID * F_FFN * 2; // 67 MB
    __hip_bfloat16* W2t  = (__hip_bfloat16*)p;  p += (size_t)E_EXP * D_HID * F_FFN * 2; // 67 MB
    __hip_bfloat16* hbuf = (__hip_bfloat16*)p;  p += (size_t)E_EXP * C_CAP * F_FFN * 2; // 134 MB

    hipMemsetAsync(d_out, 0, (size_t)out_size * sizeof(float), stream);

    gating_kernel<<<T_TOK / 4, 256, 0, stream>>>(x, Wg, gatesT);
    aux_kernel<<<1, 256, 0, stream>>>(gatesT, out + (size_t)T_TOK * D_HID);
    topk_kernel<<<E_EXP, 1024, 0, stream>>>(gatesT, topidx, topval);

    // bf16 conversions / weight transposes
    cvt_bf16_kernel<<<(T_TOK * D_HID / 4 + 255) / 256, 256, 0, stream>>>(
        x, x_bf, T_TOK * D_HID / 4);
    {
        dim3 g(F_FFN / 32, D_HID / 32, E_EXP);   // W1 [D,F] -> W1t [F,D]
        transpose_bf16_kernel<<<g, 256, 0, stream>>>(W1, W1t, D_HID, F_FFN);
    }
    {
        dim3 g(D_HID / 32, F_FFN / 32, E_EXP);   // W2 [F,D] -> W2t [D,F]
        transpose_bf16_kernel<<<g, 256, 0, stream>>>(W2, W2t, F_FFN, D_HID);
    }

    // Batched expert FFN
    {
        dim3 g(F_FFN / TN, C_CAP / TM, E_EXP);   // (32, 16, 8)
        gemm1_kernel<<<g, 256, 0, stream>>>(x_bf, W1t, b1, topidx, hbuf);
    }
    {
        dim3 g(D_HID / TN, C_CAP / TM, E_EXP);   // (8, 16, 8)
        gemm2_kernel<<<g, 256, 0, stream>>>(hbuf, W2t, b2, topidx, topval, out);
    }
}

// Round 3
// 1016.621 us; speedup vs baseline: 4.6822x; 1.0503x over previous
//
#include <hip/hip_runtime.h>
#include <hip/hip_bf16.h>

// Problem constants
#define T_TOK 8192
#define E_EXP 8
#define D_HID 1024
#define F_FFN 4096
#define C_CAP 2048   // T * 2.0 / E

// MFMA GEMM tiling
#define TM 128
#define TN 128
#define BK 32

typedef __attribute__((ext_vector_type(8))) short bf16x8;  // 8 bf16 (4 VGPRs)
typedef __attribute__((ext_vector_type(4))) float f32x4;   // 4 fp32 acc

// Async global->LDS, 16 B per lane. LDS dest is wave-uniform base + lane*16;
// source address may be per-lane (gather OK).
__device__ __forceinline__ void load_lds16(const void* g, void* l) {
    __builtin_amdgcn_global_load_lds(
        (const __attribute__((address_space(1))) unsigned int*)g,
        (__attribute__((address_space(3))) unsigned int*)l, 16, 0, 0);
}

// gelu(v) = 0.5 v (1 + tanh(u)) = v * sigmoid(2u), 2u = 1.595769 v + 0.0713548 v^3
// __expf -> v_exp_f32; ~12 cyc vs ~40+ for libm tanhf. Error ~1e-6 rel.
__device__ __forceinline__ float gelu_fast(float v) {
    float z = v * (1.5957691216057308f + 0.07135481627f * v * v);
    return v / (1.0f + __expf(-z));
}

// ---------------------------------------------------------------------------
// Kernel 1: router gating (fp32 exact). One wave per token.
// ---------------------------------------------------------------------------
__global__ __launch_bounds__(256) void gating_kernel(
    const float* __restrict__ x, const float* __restrict__ Wg,
    float* __restrict__ gatesT)
{
    const int token = blockIdx.x * 4 + (threadIdx.x >> 6);
    const int lane  = threadIdx.x & 63;
    const float* xr = x + (size_t)token * D_HID;

    float acc[E_EXP];
#pragma unroll
    for (int e = 0; e < E_EXP; ++e) acc[e] = 0.0f;

    for (int c = 0; c < D_HID; c += 64) {
        float xv = xr[c + lane];
        const float* wr = Wg + (size_t)(c + lane) * E_EXP;
#pragma unroll
        for (int e = 0; e < E_EXP; ++e) acc[e] += xv * wr[e];
    }
#pragma unroll
    for (int e = 0; e < E_EXP; ++e) {
        for (int off = 32; off; off >>= 1) acc[e] += __shfl_down(acc[e], off);
    }
    if (lane == 0) {
        float m = acc[0];
#pragma unroll
        for (int e = 1; e < E_EXP; ++e) m = fmaxf(m, acc[e]);
        float ex[E_EXP];
        float s = 0.0f;
#pragma unroll
        for (int e = 0; e < E_EXP; ++e) { ex[e] = expf(acc[e] - m); s += ex[e]; }
        float inv = 1.0f / s;
#pragma unroll
        for (int e = 0; e < E_EXP; ++e) gatesT[(size_t)e * T_TOK + token] = ex[e] * inv;
    }
}

// ---------------------------------------------------------------------------
// Kernel 2: aux loss = E * (C/T) * mean(gates)  (frac_routed == C/T exactly)
// ---------------------------------------------------------------------------
__global__ __launch_bounds__(256) void aux_kernel(
    const float* __restrict__ gatesT, float* __restrict__ aux_out)
{
    float s = 0.0f;
    for (int i = threadIdx.x; i < T_TOK * E_EXP; i += 256) s += gatesT[i];
    for (int off = 32; off; off >>= 1) s += __shfl_down(s, off);
    __shared__ float red[4];
    if ((threadIdx.x & 63) == 0) red[threadIdx.x >> 6] = s;
    __syncthreads();
    if (threadIdx.x == 0) {
        float tot = red[0] + red[1] + red[2] + red[3];
        float frac = (float)C_CAP / (float)T_TOK;
        aux_out[0] = (float)E_EXP * frac * (tot / (float)T_TOK);
    }
}

// ---------------------------------------------------------------------------
// Kernel 3: exact per-expert top-C bitonic sort (64-bit keys, jax tie-break).
// Also builds the token -> (expert, slot) inverse map for the combine pass.
// ---------------------------------------------------------------------------
__global__ __launch_bounds__(1024) void topk_kernel(
    const float* __restrict__ gatesT, int* __restrict__ topidx,
    float* __restrict__ topval, int* __restrict__ cnt, int* __restrict__ inv)
{
    __shared__ unsigned long long keys[T_TOK];
    const int e = blockIdx.x;
    const float* row = gatesT + (size_t)e * T_TOK;

    for (int i = threadIdx.x; i < T_TOK; i += blockDim.x) {
        unsigned int b = __float_as_uint(row[i]);
        b = (b & 0x80000000u) ? ~b : (b | 0x80000000u);
        keys[i] = ((unsigned long long)b << 32) | (unsigned int)(T_TOK - 1 - i);
    }
    __syncthreads();

    for (int k = 2; k <= T_TOK; k <<= 1) {
        for (int j = k >> 1; j > 0; j >>= 1) {
            for (int i = threadIdx.x; i < T_TOK; i += blockDim.x) {
                int p = i ^ j;
                if (p > i) {
                    bool desc = ((i & k) == 0);
                    unsigned long long a = keys[i];
                    unsigned long long b = keys[p];
                    bool sw = desc ? (a < b) : (a > b);
                    if (sw) { keys[i] = b; keys[p] = a; }
                }
            }
            __syncthreads();
        }
    }

    for (int c = threadIdx.x; c < C_CAP; c += blockDim.x) {
        unsigned long long kk = keys[c];
        int idx = T_TOK - 1 - (int)(kk & 0xFFFFFFFFu);
        unsigned int b = (unsigned int)(kk >> 32);
        b = (b & 0x80000000u) ? (b & 0x7FFFFFFFu) : ~b;
        topidx[e * C_CAP + c] = idx;
        topval[e * C_CAP + c] = __uint_as_float(b);
        int slot = atomicAdd(&cnt[idx], 1);   // <=8 entries per token (1/expert)
        inv[idx * E_EXP + slot] = e * C_CAP + c;
    }
}

// ---------------------------------------------------------------------------
// Kernel 4: fp32 -> bf16 elementwise (x), vectorized.
// ---------------------------------------------------------------------------
__global__ __launch_bounds__(256) void cvt_bf16_kernel(
    const float* __restrict__ in, __hip_bfloat16* __restrict__ out, int n4)
{
    int i = blockIdx.x * 256 + threadIdx.x;
    if (i >= n4) return;
    float4 v = ((const float4*)in)[i];
    union { __hip_bfloat16 h[4]; short4 s; } u;
    u.h[0] = __float2bfloat16(v.x); u.h[1] = __float2bfloat16(v.y);
    u.h[2] = __float2bfloat16(v.z); u.h[3] = __float2bfloat16(v.w);
    ((short4*)out)[i] = u.s;
}

// ---------------------------------------------------------------------------
// Kernel 5: per-expert transpose+convert: [E][R][Cn] fp32 -> [E][Cn][R] bf16.
// 64x64 tile; float4 coalesced reads; packed 16 B coalesced writes.
// LDS stride 65 floats: both phases <=2-way bank aliasing (free).
// ---------------------------------------------------------------------------
__global__ __launch_bounds__(256) void transpose_bf16_kernel(
    const float* __restrict__ in, __hip_bfloat16* __restrict__ out,
    int R, int Cn)
{
    __shared__ float tile[64][65];
    const int e = blockIdx.z;
    in  += (size_t)e * R * Cn;
    out += (size_t)e * R * Cn;
    const int c0 = blockIdx.x * 64, r0 = blockIdx.y * 64;
    const int tid = threadIdx.x;

    const int lr = tid >> 4, lc4 = (tid & 15) * 4;
#pragma unroll
    for (int it = 0; it < 4; ++it) {
        int r = lr + it * 16;
        float4 v = *(const float4*)(in + (size_t)(r0 + r) * Cn + c0 + lc4);
        tile[r][lc4 + 0] = v.x; tile[r][lc4 + 1] = v.y;
        tile[r][lc4 + 2] = v.z; tile[r][lc4 + 3] = v.w;
    }
    __syncthreads();

    const int ocb = tid >> 3, j0 = (tid & 7) * 8;
#pragma unroll
    for (int it = 0; it < 2; ++it) {
        int oc = ocb + it * 32;
        union { __hip_bfloat16 h[8]; uint4 v; } u;
#pragma unroll
        for (int j = 0; j < 8; ++j) u.h[j] = __float2bfloat16(tile[j0 + j][oc]);
        *(uint4*)(out + (size_t)(c0 + oc) * R + r0 + j0) = u.v;
    }
}

// ---------------------------------------------------------------------------
// Kernel 6: GEMM1 (all experts): h[e] = gelu(gather(x)[C,D] @ W1t[e]^T + b1[e])
// m97 structure: 128x128 tile, BK=32, global_load_lds x16. Epilogue transposes
// through LDS (stride 132, conflict-free) for 16 B coalesced bf16 stores.
// ---------------------------------------------------------------------------
__global__ __launch_bounds__(256) void gemm1_kernel(
    const __hip_bfloat16* __restrict__ xb,   // [T][D]
    const __hip_bfloat16* __restrict__ W1t,  // [E][F][D]
    const float* __restrict__ b1,            // [E][F]
    const int* __restrict__ topidx,          // [E][C]
    __hip_bfloat16* __restrict__ h)          // [E][C][F]
{
    __shared__ __align__(16) char smem[64 * 132 * 2];  // 16896 B >= staging 16384 B
    __hip_bfloat16* As = (__hip_bfloat16*)smem;        // [128][32]
    __hip_bfloat16* Bs = As + TM * BK;                 // [128][32]

    const int e   = blockIdx.z;
    const int n0  = blockIdx.x * TN;
    const int m0  = blockIdx.y * TM;
    const int tid = threadIdx.x;
    const int w = tid >> 6, lane = tid & 63;

    const int sr0 = (w * 2 + 0) * 16 + (lane >> 2);
    const int sr1 = (w * 2 + 1) * 16 + (lane >> 2);
    const int skp = (lane & 3) * 8;

    const __hip_bfloat16* W = W1t + (size_t)e * F_FFN * D_HID;

    const int tok0 = topidx[e * C_CAP + m0 + sr0];
    const int tok1 = topidx[e * C_CAP + m0 + sr1];
    const __hip_bfloat16* asrc0 = xb + (size_t)tok0 * D_HID + skp;
    const __hip_bfloat16* asrc1 = xb + (size_t)tok1 * D_HID + skp;
    const __hip_bfloat16* bsrc0 = W + (size_t)(n0 + sr0) * D_HID + skp;
    const __hip_bfloat16* bsrc1 = W + (size_t)(n0 + sr1) * D_HID + skp;

    __hip_bfloat16* adst0 = As + (w * 2 + 0) * 512;
    __hip_bfloat16* adst1 = As + (w * 2 + 1) * 512;
    __hip_bfloat16* bdst0 = Bs + (w * 2 + 0) * 512;
    __hip_bfloat16* bdst1 = Bs + (w * 2 + 1) * 512;

    const int wr = w >> 1, wc = w & 1;
    const int fr = lane & 15;
    const int fq = (lane >> 4) * 8;
    int aoff[4], boff[4];
#pragma unroll
    for (int i = 0; i < 4; ++i) {
        aoff[i] = (wr * 64 + i * 16 + fr) * BK + fq;
        boff[i] = (wc * 64 + i * 16 + fr) * BK + fq;
    }

    f32x4 acc[4][4];
#pragma unroll
    for (int mi = 0; mi < 4; ++mi)
#pragma unroll
        for (int ni = 0; ni < 4; ++ni) acc[mi][ni] = (f32x4){0.f, 0.f, 0.f, 0.f};

    for (int k0 = 0; k0 < D_HID; k0 += BK) {
        __syncthreads();
        load_lds16(asrc0 + k0, adst0);
        load_lds16(asrc1 + k0, adst1);
        load_lds16(bsrc0 + k0, bdst0);
        load_lds16(bsrc1 + k0, bdst1);
        __syncthreads();

        bf16x8 af[4], bfm[4];
#pragma unroll
        for (int i = 0; i < 4; ++i) af[i]  = *(const bf16x8*)(As + aoff[i]);
#pragma unroll
        for (int i = 0; i < 4; ++i) bfm[i] = *(const bf16x8*)(Bs + boff[i]);
#pragma unroll
        for (int mi = 0; mi < 4; ++mi)
#pragma unroll
            for (int ni = 0; ni < 4; ++ni)
                acc[mi][ni] = __builtin_amdgcn_mfma_f32_16x16x32_bf16(
                    af[mi], bfm[ni], acc[mi][ni], 0, 0, 0);
    }

    // Epilogue: bias + gelu, LDS transpose (64 rows/pass), coalesced stores.
    float b1v[4];
#pragma unroll
    for (int ni = 0; ni < 4; ++ni)
        b1v[ni] = b1[e * F_FFN + n0 + wc * 64 + ni * 16 + fr];

    __hip_bfloat16* tile = (__hip_bfloat16*)smem;   // [64][stride 132]
    const int q4 = (lane >> 4) * 4;
#pragma unroll
    for (int p = 0; p < 2; ++p) {
        __syncthreads();
        if (wr == p) {
#pragma unroll
            for (int mi = 0; mi < 4; ++mi)
#pragma unroll
                for (int ni = 0; ni < 4; ++ni)
#pragma unroll
                    for (int r = 0; r < 4; ++r) {
                        int rl  = mi * 16 + q4 + r;
                        int col = wc * 64 + ni * 16 + fr;
                        float v = acc[mi][ni][r] + b1v[ni];
                        tile[rl * 132 + col] = __float2bfloat16(gelu_fast(v));
                    }
        }
        __syncthreads();
#pragma unroll
        for (int it = 0; it < 4; ++it) {
            int rl = it * 16 + (tid >> 4);
            int cb = (tid & 15) * 8;
            uint2 lo = *(const uint2*)(tile + rl * 132 + cb);
            uint2 hi = *(const uint2*)(tile + rl * 132 + cb + 4);
            uint4 vv = {lo.x, lo.y, hi.x, hi.y};
            *(uint4*)(h + ((size_t)e * C_CAP + m0 + p * 64 + rl) * F_FFN + n0 + cb) = vv;
        }
    }
}

// ---------------------------------------------------------------------------
// Kernel 7: GEMM2 (all experts): yo[e][c] = (h[e] @ W2t[e]^T + b2[e]) * gate
// No atomics: gate-weighted rows land in yo[E][C][D] fp32; combine gathers.
// ---------------------------------------------------------------------------
__global__ __launch_bounds__(256) void gemm2_kernel(
    const __hip_bfloat16* __restrict__ h,    // [E][C][F]
    const __hip_bfloat16* __restrict__ W2t,  // [E][D][F]
    const float* __restrict__ b2,            // [E][D]
    const float* __restrict__ topval,        // [E][C]
    float* __restrict__ yo)                  // [E][C][D]
{
    __shared__ __hip_bfloat16 As[TM * BK];
    __shared__ __hip_bfloat16 Bs[TN * BK];

    const int e   = blockIdx.z;
    const int n0  = blockIdx.x * TN;
    const int m0  = blockIdx.y * TM;
    const int tid = threadIdx.x;
    const int w = tid >> 6, lane = tid & 63;

    const int sr0 = (w * 2 + 0) * 16 + (lane >> 2);
    const int sr1 = (w * 2 + 1) * 16 + (lane >> 2);
    const int skp = (lane & 3) * 8;

    const __hip_bfloat16* A = h + (size_t)e * C_CAP * F_FFN;
    const __hip_bfloat16* W = W2t + (size_t)e * D_HID * F_FFN;

    const __hip_bfloat16* asrc0 = A + (size_t)(m0 + sr0) * F_FFN + skp;
    const __hip_bfloat16* asrc1 = A + (size_t)(m0 + sr1) * F_FFN + skp;
    const __hip_bfloat16* bsrc0 = W + (size_t)(n0 + sr0) * F_FFN + skp;
    const __hip_bfloat16* bsrc1 = W + (size_t)(n0 + sr1) * F_FFN + skp;

    __hip_bfloat16* adst0 = As + (w * 2 + 0) * 512;
    __hip_bfloat16* adst1 = As + (w * 2 + 1) * 512;
    __hip_bfloat16* bdst0 = Bs + (w * 2 + 0) * 512;
    __hip_bfloat16* bdst1 = Bs + (w * 2 + 1) * 512;

    const int wr = w >> 1, wc = w & 1;
    const int fr = lane & 15;
    const int fq = (lane >> 4) * 8;
    int aoff[4], boff[4];
#pragma unroll
    for (int i = 0; i < 4; ++i) {
        aoff[i] = (wr * 64 + i * 16 + fr) * BK + fq;
        boff[i] = (wc * 64 + i * 16 + fr) * BK + fq;
    }

    f32x4 acc[4][4];
#pragma unroll
    for (int mi = 0; mi < 4; ++mi)
#pragma unroll
        for (int ni = 0; ni < 4; ++ni) acc[mi][ni] = (f32x4){0.f, 0.f, 0.f, 0.f};

    for (int k0 = 0; k0 < F_FFN; k0 += BK) {
        __syncthreads();
        load_lds16(asrc0 + k0, adst0);
        load_lds16(asrc1 + k0, adst1);
        load_lds16(bsrc0 + k0, bdst0);
        load_lds16(bsrc1 + k0, bdst1);
        __syncthreads();

        bf16x8 af[4], bfm[4];
#pragma unroll
        for (int i = 0; i < 4; ++i) af[i]  = *(const bf16x8*)(As + aoff[i]);
#pragma unroll
        for (int i = 0; i < 4; ++i) bfm[i] = *(const bf16x8*)(Bs + boff[i]);
#pragma unroll
        for (int mi = 0; mi < 4; ++mi)
#pragma unroll
            for (int ni = 0; ni < 4; ++ni)
                acc[mi][ni] = __builtin_amdgcn_mfma_f32_16x16x32_bf16(
                    af[mi], bfm[ni], acc[mi][ni], 0, 0, 0);
    }

    // Epilogue: bias + gate weight, plain dword stores (64 B per quarter-wave).
    const int q4 = (lane >> 4) * 4;
    float b2v[4];
#pragma unroll
    for (int ni = 0; ni < 4; ++ni)
        b2v[ni] = b2[e * D_HID + n0 + wc * 64 + ni * 16 + fr];

#pragma unroll
    for (int mi = 0; mi < 4; ++mi) {
#pragma unroll
        for (int r = 0; r < 4; ++r) {
            const int row = m0 + wr * 64 + mi * 16 + q4 + r;
            const float g = topval[e * C_CAP + row];
            float* orow = yo + ((size_t)e * C_CAP + row) * D_HID;
#pragma unroll
            for (int ni = 0; ni < 4; ++ni) {
                const int col = n0 + wc * 64 + ni * 16 + fr;
                orow[col] = (acc[mi][ni][r] + b2v[ni]) * g;
            }
        }
    }
}

// ---------------------------------------------------------------------------
// Kernel 8: combine — out[t] = sum over inv[t] entries of yo rows. One block
// per token; fully coalesced; writes every output element (no memset needed).
// ---------------------------------------------------------------------------
__global__ __launch_bounds__(256) void combine_kernel(
    const float* __restrict__ yo, const int* __restrict__ cnt,
    const int* __restrict__ inv, float* __restrict__ out)
{
    const int t = blockIdx.x;
    const int n = cnt[t];
    const int c4 = threadIdx.x * 4;
    float4 a = {0.f, 0.f, 0.f, 0.f};
    for (int k = 0; k < n; ++k) {
        int ec = inv[t * E_EXP + k];
        float4 v = *(const float4*)(yo + (size_t)ec * D_HID + c4);
        a.x += v.x; a.y += v.y; a.z += v.z; a.w += v.w;
    }
    *(float4*)(out + (size_t)t * D_HID + c4) = a;
}

// ---------------------------------------------------------------------------
extern "C" void kernel_launch(void* const* d_in, const int* in_sizes, int n_in,
                              void* d_out, int out_size, void* d_ws, size_t ws_size,
                              hipStream_t stream) {
    const float* x  = (const float*)d_in[0];   // [T, D]
    const float* Wg = (const float*)d_in[1];   // [D, E]
    const float* W1 = (const float*)d_in[2];   // [E, D, F]
    const float* b1 = (const float*)d_in[3];   // [E, F]
    const float* W2 = (const float*)d_in[4];   // [E, F, D]
    const float* b2 = (const float*)d_in[5];   // [E, D]
    float* out = (float*)d_out;                // [T*D] out ++ [1] aux

    // Workspace layout
    char* p = (char*)d_ws;
    float* gatesT = (float*)p;            p += (size_t)E_EXP * T_TOK * 4;      // 256 KB
    int*   topidx = (int*)p;              p += (size_t)E_EXP * C_CAP * 4;      // 64 KB
    float* topval = (float*)p;            p += (size_t)E_EXP * C_CAP * 4;      // 64 KB
    int*   cnt    = (int*)p;              p += (size_t)T_TOK * 4;              // 32 KB
    int*   inv    = (int*)p;              p += (size_t)T_TOK * E_EXP * 4;      // 256 KB
    __hip_bfloat16* x_bf = (__hip_bfloat16*)p;  p += (size_t)T_TOK * D_HID * 2;         // 16.8 MB
    __hip_bfloat16* W1t  = (__hip_bfloat16*)p;  p += (size_t)E_EXP * D_HID * F_FFN * 2; // 67 MB
    __hip_bfloat16* W2t  = (__hip_bfloat16*)p;  p += (size_t)E_EXP * D_HID * F_FFN * 2; // 67 MB
    __hip_bfloat16* hbuf = (__hip_bfloat16*)p;  p += (size_t)E_EXP * C_CAP * F_FFN * 2; // 134 MB
    // yo aliases W1t (dead after gemm1; gemm2 writes yo, combine reads it).
    float* yo = (float*)W1t;   // E*C*D*4 = 67 MB, exactly W1t's size

    hipMemsetAsync(cnt, 0, (size_t)T_TOK * 4, stream);

    gating_kernel<<<T_TOK / 4, 256, 0, stream>>>(x, Wg, gatesT);
    aux_kernel<<<1, 256, 0, stream>>>(gatesT, out + (size_t)T_TOK * D_HID);
    topk_kernel<<<E_EXP, 1024, 0, stream>>>(gatesT, topidx, topval, cnt, inv);

    // bf16 conversions / weight transposes
    cvt_bf16_kernel<<<(T_TOK * D_HID / 4 + 255) / 256, 256, 0, stream>>>(
        x, x_bf, T_TOK * D_HID / 4);
    {
        dim3 g(F_FFN / 64, D_HID / 64, E_EXP);   // W1 [D,F] -> W1t [F,D]
        transpose_bf16_kernel<<<g, 256, 0, stream>>>(W1, W1t, D_HID, F_FFN);
    }
    {
        dim3 g(D_HID / 64, F_FFN / 64, E_EXP);   // W2 [F,D] -> W2t [D,F]
        transpose_bf16_kernel<<<g, 256, 0, stream>>>(W2, W2t, F_FFN, D_HID);
    }

    // Batched expert FFN
    {
        dim3 g(F_FFN / TN, C_CAP / TM, E_EXP);   // (32, 16, 8)
        gemm1_kernel<<<g, 256, 0, stream>>>(x_bf, W1t, b1, topidx, hbuf);
    }
    {
        dim3 g(D_HID / TN, C_CAP / TM, E_EXP);   // (8, 16, 8)
        gemm2_kernel<<<g, 256, 0, stream>>>(hbuf, W2t, b2, topval, yo);
    }
    combine_kernel<<<T_TOK, 256, 0, stream>>>(yo, cnt, inv, out);
}